// Round 3
// baseline (9993.308 us; speedup 1.0000x reference)
//
#include <hip/hip_runtime.h>
#include <hip/hip_bf16.h>

// LSTM: L=1024, B=64, I=512, H=512, fp32 in/out.
// Persistent kernel, 256 WGs x 256 thr (1/CU). 8 clusters x 32 WGs; cluster =
// 8 batches, wave = 16 gate rows (4 h-idx x 4 gates). Weights in VGPRs.
// NO barrier: h exchanged as tagged u32 (tag=t+1 in hi16, bf16 h in lo16)
// through a MALL-resident double buffer in d_ws, accessed with relaxed
// agent-scope (sc0 sc1 bypass) loads/stores. Consumers poll their own data;
// buffer-reuse safety follows from the full-K data dependency (waves can
// never be 2 steps apart at conflicting accesses).

typedef __attribute__((ext_vector_type(8))) short bf16x8;
typedef __attribute__((ext_vector_type(4))) float f32x4;

#define NT 1024
#define NB 64
#define NH 512
#define NI 512
#define HX_BYTES (2 * NB * NH * 4)   // 256 KiB double buffer of u32

__device__ __forceinline__ bf16x8 pack8(float4 a, float4 b) {
    union U2 { __hip_bfloat162 h; unsigned int u; } c0, c1, c2, c3;
    c0.h = __float22bfloat162_rn(make_float2(a.x, a.y));
    c1.h = __float22bfloat162_rn(make_float2(a.z, a.w));
    c2.h = __float22bfloat162_rn(make_float2(b.x, b.y));
    c3.h = __float22bfloat162_rn(make_float2(b.z, b.w));
    union R { bf16x8 v; unsigned int u[4]; } r;
    r.u[0] = c0.u; r.u[1] = c1.u; r.u[2] = c2.u; r.u[3] = c3.u;
    return r.v;
}

__device__ __forceinline__ float sigm(float v) {
    return 1.0f / (1.0f + __expf(-v));
}
__device__ __forceinline__ float tanh_f(float v) {
    float e = __expf(-2.0f * fabsf(v));        // in (0,1], no overflow
    float r = (1.0f - e) / (1.0f + e);
    return copysignf(r, v);
}

__global__ __launch_bounds__(256, 1) void lstm_fused(
    const float* __restrict__ x,
    const float* __restrict__ h0,
    const float* __restrict__ c0,
    const float* __restrict__ Wf, const float* __restrict__ Bf,
    const float* __restrict__ Wi, const float* __restrict__ Bi,
    const float* __restrict__ Wc, const float* __restrict__ Bc,
    const float* __restrict__ Wo, const float* __restrict__ Bo,
    float* __restrict__ out,
    unsigned int* __restrict__ hx)        // [2][NB][NH] tagged u32
{
    const int tid  = threadIdx.x;
    const int wv   = tid >> 6;            // wave 0..3
    const int lane = tid & 63;
    const int n    = lane & 15;           // D col (gate row within wave tile)
    const int kg   = lane >> 4;           // k-group 0..3
    const int cl   = blockIdx.x & 7;      // cluster (XCD-swizzle heuristic)
    const int wg   = blockIdx.x >> 3;     // WG within cluster, 0..31

    const int jj = (wv << 2) + (n >> 2);          // 0..15 within WG
    const int j  = (wg << 4) + jj;                // global h index
    const int g  = n & 3;                         // 0=f 1=i 2=c 3=o

    const float* Wg = (g == 0) ? Wf : (g == 1) ? Wi : (g == 2) ? Wc : Wo;
    const float* Bg = (g == 0) ? Bf : (g == 1) ? Bi : (g == 2) ? Bc : Bo;

    const int m_a   = (n < 8) ? n : 7;            // A-row batch (8..15 dup)
    const int bglob = cl * 8 + m_a;

    // ---- prologue: static B-fragments (weights, bf16) into VGPRs ----
    bf16x8 bfrag[32];
    {
        const float* wrow = Wg + (size_t)j * (NH + NI);
        #pragma unroll
        for (int kb = 0; kb < 32; ++kb) {
            const float* p = wrow + kb * 32 + kg * 8;
            float4 w0 = *(const float4*)(p);
            float4 w1 = *(const float4*)(p + 4);
            bfrag[kb] = pack8(w0, w1);
        }
    }
    const float bias_v = Bg[j];

    // ---- C state in registers of "active" lanes ----
    const bool active = (g == 0) && (kg < 2);     // 8 lanes/wave x 4 regs
    float Cst[4];
    #pragma unroll
    for (int r = 0; r < 4; ++r)
        Cst[r] = active ? c0[(size_t)(cl * 8 + kg * 4 + r) * NH + j] : 0.0f;

    for (int t = 0; t < NT; ++t) {
        // -- x fragments + x-partial MFMAs (independent of other waves) --
        const float* xrow = x + ((size_t)t * NB + bglob) * NI;
        bf16x8 xfrag[16];
        #pragma unroll
        for (int q = 0; q < 16; ++q) {
            const float* p = xrow + q * 32 + kg * 8;
            float4 v0 = *(const float4*)(p);
            float4 v1 = *(const float4*)(p + 4);
            xfrag[q] = pack8(v0, v1);
        }
        f32x4 a0 = {bias_v, bias_v, bias_v, bias_v};
        f32x4 a1 = {0.f, 0.f, 0.f, 0.f};
        f32x4 a2 = {0.f, 0.f, 0.f, 0.f};
        f32x4 a3 = {0.f, 0.f, 0.f, 0.f};
        #pragma unroll
        for (int q = 0; q < 16; q += 4) {
            a0 = __builtin_amdgcn_mfma_f32_16x16x32_bf16(xfrag[q],     bfrag[16 + q],     a0, 0, 0, 0);
            a1 = __builtin_amdgcn_mfma_f32_16x16x32_bf16(xfrag[q + 1], bfrag[16 + q + 1], a1, 0, 0, 0);
            a2 = __builtin_amdgcn_mfma_f32_16x16x32_bf16(xfrag[q + 2], bfrag[16 + q + 2], a2, 0, 0, 0);
            a3 = __builtin_amdgcn_mfma_f32_16x16x32_bf16(xfrag[q + 3], bfrag[16 + q + 3], a3, 0, 0, 0);
        }

        // -- h fragments: tagged-poll from exchange buffer --
        bf16x8 hfrag[16];
        if (t == 0) {
            const float* hrow = h0 + (size_t)bglob * NH;
            #pragma unroll
            for (int q = 0; q < 16; ++q) {
                const float* p = hrow + q * 32 + kg * 8;
                float4 v0 = *(const float4*)(p);
                float4 v1 = *(const float4*)(p + 4);
                hfrag[q] = pack8(v0, v1);
            }
        } else {
            const unsigned int tag = (unsigned int)t;   // producer t-1 wrote t
            const unsigned long long pat =
                ((unsigned long long)tag << 48) | ((unsigned long long)tag << 16);
            const unsigned int* hrow =
                hx + ((size_t)((t - 1) & 1) * NB + bglob) * NH;
            unsigned long long hraw[64];
            int guard = 1 << 20;
            for (;;) {
                #pragma unroll
                for (int q = 0; q < 16; ++q) {
                    const unsigned long long* p =
                        (const unsigned long long*)(hrow + q * 32 + kg * 8);
                    hraw[4 * q + 0] = __hip_atomic_load(p + 0, __ATOMIC_RELAXED, __HIP_MEMORY_SCOPE_AGENT);
                    hraw[4 * q + 1] = __hip_atomic_load(p + 1, __ATOMIC_RELAXED, __HIP_MEMORY_SCOPE_AGENT);
                    hraw[4 * q + 2] = __hip_atomic_load(p + 2, __ATOMIC_RELAXED, __HIP_MEMORY_SCOPE_AGENT);
                    hraw[4 * q + 3] = __hip_atomic_load(p + 3, __ATOMIC_RELAXED, __HIP_MEMORY_SCOPE_AGENT);
                }
                unsigned long long diff = 0;
                #pragma unroll
                for (int i = 0; i < 64; ++i) diff |= hraw[i] ^ pat;
                if (!(diff & 0xFFFF0000FFFF0000ULL)) break;
                if (--guard == 0) break;              // hang safety
            }
            // extract bf16 pairs: (h1<<16)|h0 from each u64's two low halves
            #pragma unroll
            for (int q = 0; q < 16; ++q) {
                union { bf16x8 v; unsigned int u[4]; } un;
                #pragma unroll
                for (int k = 0; k < 4; ++k) {
                    unsigned long long w = hraw[4 * q + k];
                    un.u[k] = ((unsigned int)w & 0xFFFFu) |
                              (((unsigned int)(w >> 32)) << 16);
                }
                hfrag[q] = un.v;
            }
        }

        #pragma unroll
        for (int q = 0; q < 16; q += 4) {
            a0 = __builtin_amdgcn_mfma_f32_16x16x32_bf16(hfrag[q],     bfrag[q],     a0, 0, 0, 0);
            a1 = __builtin_amdgcn_mfma_f32_16x16x32_bf16(hfrag[q + 1], bfrag[q + 1], a1, 0, 0, 0);
            a2 = __builtin_amdgcn_mfma_f32_16x16x32_bf16(hfrag[q + 2], bfrag[q + 2], a2, 0, 0, 0);
            a3 = __builtin_amdgcn_mfma_f32_16x16x32_bf16(hfrag[q + 3], bfrag[q + 3], a3, 0, 0, 0);
        }
        f32x4 acc = (a0 + a1) + (a2 + a3);

        // -- gather f/i/c/o in 4-lane groups, elementwise, publish h --
        unsigned int* hxout = hx + (size_t)(t & 1) * NB * NH;
        const unsigned int otag = ((unsigned int)(t + 1)) << 16;
        #pragma unroll
        for (int r = 0; r < 4; ++r) {
            float fv = acc[r];
            float iv = __shfl_xor(fv, 1);
            float gv = __shfl_xor(fv, 2);
            float ov = __shfl_xor(fv, 3);
            if (active) {
                float ft = sigm(fv);
                float it = sigm(iv);
                float gt = tanh_f(gv);
                float ot = sigm(ov);
                float Cn = ft * Cst[r] + it * gt;
                Cst[r] = Cn;
                float ht = ot * tanh_f(Cn);
                int m = kg * 4 + r;                   // batch within cluster
                out[((size_t)t * NB + cl * 8 + m) * NH + j] = ht;
                __hip_bfloat16 hb = __float2bfloat16(ht);
                unsigned int hv32 = otag | (unsigned int)(*(unsigned short*)&hb);
                unsigned int* ep = hxout + (size_t)(cl * 8 + m) * NH + j;
                __hip_atomic_store(ep, hv32, __ATOMIC_RELAXED,
                                   __HIP_MEMORY_SCOPE_AGENT);
            }
        }
        // no fence, no syncthreads, no counter: readers poll the tags.
    }
}

extern "C" void kernel_launch(void* const* d_in, const int* in_sizes, int n_in,
                              void* d_out, int out_size, void* d_ws, size_t ws_size,
                              hipStream_t stream) {
    const float* x  = (const float*)d_in[0];
    const float* h0 = (const float*)d_in[1];
    const float* c0 = (const float*)d_in[2];
    const float* Wf = (const float*)d_in[3];
    const float* Bf = (const float*)d_in[4];
    const float* Wi = (const float*)d_in[5];
    const float* Bi = (const float*)d_in[6];
    const float* Wc = (const float*)d_in[7];
    const float* Bc = (const float*)d_in[8];
    const float* Wo = (const float*)d_in[9];
    const float* Bo = (const float*)d_in[10];
    float* out = (float*)d_out;
    unsigned int* hx = (unsigned int*)d_ws;

    // Zero the tagged exchange buffer each launch: tag 0 is invalid, so all
    // polls wait for this launch's writes (stale cross-replay tags erased).
    hipMemsetAsync(d_ws, 0, HX_BYTES, stream);

    lstm_fused<<<dim3(256), dim3(256), 0, stream>>>(
        x, h0, c0, Wf, Bf, Wi, Bi, Wc, Bc, Wo, Bo, out, hx);
}

// Round 5
// 6583.930 us; speedup vs baseline: 1.5178x; 1.5178x over previous
//
#include <hip/hip_runtime.h>
#include <hip/hip_bf16.h>

// LSTM: L=1024, B=64, I=512, H=512, fp32 in/out.
// Persistent kernel, 256 WGs x 256 thr (1 WG/CU). 8 clusters x 32 WGs;
// cluster = 8 batches; wave = 16 gate rows (4 h-idx x 4 gates). Weights live
// in VGPRs as MFMA B-fragments; C state in registers.
// Exchange protocol (all-MALL, proven coherent in rounds 2/3):
//   producer: h stores (relaxed agent u16) -> s_waitcnt vmcnt(0) -> one 4B
//             per-wave flag store (relaxed agent).  No RMW, no syncthreads.
//   consumer: poll all 128 cluster flags with ONE u64 atomic load per lane,
//             then load h as u64 relaxed agent atomics (compiler-tracked).
// Buffer reuse safe: passing the wait for step t proves every wave finished
// step t-1, hence finished READING buffer (t-2)&1 == t&1 before we overwrite.

typedef __attribute__((ext_vector_type(8))) short bf16x8;
typedef __attribute__((ext_vector_type(4))) float f32x4;

#define NT 1024
#define NB 64
#define NH 512
#define NI 512

#define FLAGS_OFF 0        // u32[8][128]  (4 KiB)
#define HX_OFF    4096     // u16[2][64][512] (128 KiB)
#define ZERO_BYTES 4096

__device__ __forceinline__ bf16x8 pack8(float4 a, float4 b) {
    union U2 { __hip_bfloat162 h; unsigned int u; } c0, c1, c2, c3;
    c0.h = __float22bfloat162_rn(make_float2(a.x, a.y));
    c1.h = __float22bfloat162_rn(make_float2(a.z, a.w));
    c2.h = __float22bfloat162_rn(make_float2(b.x, b.y));
    c3.h = __float22bfloat162_rn(make_float2(b.z, b.w));
    union R { bf16x8 v; unsigned int u[4]; } r;
    r.u[0] = c0.u; r.u[1] = c1.u; r.u[2] = c2.u; r.u[3] = c3.u;
    return r.v;
}

__device__ __forceinline__ float sigm(float v) {
    return 1.0f / (1.0f + __expf(-v));
}
__device__ __forceinline__ float tanh_f(float v) {
    float e = __expf(-2.0f * fabsf(v));        // in (0,1], no overflow
    float r = (1.0f - e) / (1.0f + e);
    return copysignf(r, v);
}

__global__ __launch_bounds__(256, 1) void lstm_fused(
    const float* __restrict__ x,
    const float* __restrict__ h0,
    const float* __restrict__ c0,
    const float* __restrict__ Wf, const float* __restrict__ Bf,
    const float* __restrict__ Wi, const float* __restrict__ Bi,
    const float* __restrict__ Wc, const float* __restrict__ Bc,
    const float* __restrict__ Wo, const float* __restrict__ Bo,
    float* __restrict__ out,
    unsigned char* __restrict__ ws)
{
    unsigned int*   flags = (unsigned int*)(ws + FLAGS_OFF);
    unsigned short* hx    = (unsigned short*)(ws + HX_OFF);

    const int tid  = threadIdx.x;
    const int wv   = tid >> 6;            // wave 0..3
    const int lane = tid & 63;
    const int n    = lane & 15;           // D col (gate row within wave tile)
    const int kg   = lane >> 4;           // k-group 0..3
    const int cl   = blockIdx.x & 7;      // cluster (XCD-swizzle heuristic)
    const int wg   = blockIdx.x >> 3;     // WG within cluster, 0..31

    const int jj = (wv << 2) + (n >> 2);          // 0..15 within WG
    const int j  = (wg << 4) + jj;                // global h index
    const int g  = n & 3;                         // 0=f 1=i 2=c 3=o

    const float* Wg = (g == 0) ? Wf : (g == 1) ? Wi : (g == 2) ? Wc : Wo;
    const float* Bg = (g == 0) ? Bf : (g == 1) ? Bi : (g == 2) ? Bc : Bo;

    const int m_a   = (n < 8) ? n : 7;            // A-row batch (8..15 dup)
    const int bglob = cl * 8 + m_a;

    // ---- prologue: static B-fragments (weights, bf16) into VGPRs ----
    bf16x8 bfrag[32];
    {
        const float* wrow = Wg + (size_t)j * (NH + NI);
        #pragma unroll
        for (int kb = 0; kb < 32; ++kb) {
            const float* p = wrow + kb * 32 + kg * 8;
            float4 w0 = *(const float4*)(p);
            float4 w1 = *(const float4*)(p + 4);
            bfrag[kb] = pack8(w0, w1);
        }
    }
    const float bias_v = Bg[j];

    const bool active = (g == 0) && (kg < 2);     // 8 lanes/wave x 4 regs
    float Cst[4];
    #pragma unroll
    for (int r = 0; r < 4; ++r)
        Cst[r] = active ? c0[(size_t)(cl * 8 + kg * 4 + r) * NH + j] : 0.0f;

    unsigned int* fb = flags + cl * 128;          // 128 wave-flags, 512 B
    const int myflag = wg * 4 + wv;

    for (int t = 0; t < NT; ++t) {
        // -- x fragments + x-partial MFMAs (independent of other waves) --
        const float* xrow = x + ((size_t)t * NB + bglob) * NI;
        bf16x8 xfrag[16];
        #pragma unroll
        for (int q = 0; q < 16; ++q) {
            const float* p = xrow + q * 32 + kg * 8;
            float4 v0 = *(const float4*)(p);
            float4 v1 = *(const float4*)(p + 4);
            xfrag[q] = pack8(v0, v1);
        }
        f32x4 a0 = {bias_v, bias_v, bias_v, bias_v};
        f32x4 a1 = {0.f, 0.f, 0.f, 0.f};
        f32x4 a2 = {0.f, 0.f, 0.f, 0.f};
        f32x4 a3 = {0.f, 0.f, 0.f, 0.f};
        #pragma unroll
        for (int q = 0; q < 16; q += 4) {
            a0 = __builtin_amdgcn_mfma_f32_16x16x32_bf16(xfrag[q],     bfrag[16 + q],     a0, 0, 0, 0);
            a1 = __builtin_amdgcn_mfma_f32_16x16x32_bf16(xfrag[q + 1], bfrag[16 + q + 1], a1, 0, 0, 0);
            a2 = __builtin_amdgcn_mfma_f32_16x16x32_bf16(xfrag[q + 2], bfrag[16 + q + 2], a2, 0, 0, 0);
            a3 = __builtin_amdgcn_mfma_f32_16x16x32_bf16(xfrag[q + 3], bfrag[16 + q + 3], a3, 0, 0, 0);
        }

        // -- wait: all 128 producer waves of step t-1 (one u64 load/lane) --
        if (t > 0) {
            const unsigned int tgt = (unsigned int)t;
            const unsigned long long* fp =
                (const unsigned long long*)fb + lane;
            int guard = 1 << 20;
            for (;;) {
                unsigned long long fv = __hip_atomic_load(
                    fp, __ATOMIC_RELAXED, __HIP_MEMORY_SCOPE_AGENT);
                bool ok = ((unsigned int)fv >= tgt) &&
                          ((unsigned int)(fv >> 32) >= tgt);
                if (__all(ok)) break;
                if (--guard == 0) break;          // hang safety
                __builtin_amdgcn_s_sleep(1);
            }
            __builtin_amdgcn_sched_barrier(0);    // keep h-loads after spin
        }

        // -- h fragments --
        bf16x8 hfrag[16];
        if (t == 0) {
            const float* hrow = h0 + (size_t)bglob * NH;
            #pragma unroll
            for (int q = 0; q < 16; ++q) {
                const float* p = hrow + q * 32 + kg * 8;
                float4 v0 = *(const float4*)(p);
                float4 v1 = *(const float4*)(p + 4);
                hfrag[q] = pack8(v0, v1);
            }
        } else {
            const unsigned short* hrow =
                hx + ((size_t)((t - 1) & 1) * NB + bglob) * NH;
            #pragma unroll
            for (int q = 0; q < 16; ++q) {
                const unsigned long long* p =
                    (const unsigned long long*)(hrow + q * 32 + kg * 8);
                union { bf16x8 v; unsigned long long u[2]; } un;
                un.u[0] = __hip_atomic_load(p,     __ATOMIC_RELAXED,
                                            __HIP_MEMORY_SCOPE_AGENT);
                un.u[1] = __hip_atomic_load(p + 1, __ATOMIC_RELAXED,
                                            __HIP_MEMORY_SCOPE_AGENT);
                hfrag[q] = un.v;
            }
        }

        #pragma unroll
        for (int q = 0; q < 16; q += 4) {
            a0 = __builtin_amdgcn_mfma_f32_16x16x32_bf16(hfrag[q],     bfrag[q],     a0, 0, 0, 0);
            a1 = __builtin_amdgcn_mfma_f32_16x16x32_bf16(hfrag[q + 1], bfrag[q + 1], a1, 0, 0, 0);
            a2 = __builtin_amdgcn_mfma_f32_16x16x32_bf16(hfrag[q + 2], bfrag[q + 2], a2, 0, 0, 0);
            a3 = __builtin_amdgcn_mfma_f32_16x16x32_bf16(hfrag[q + 3], bfrag[q + 3], a3, 0, 0, 0);
        }
        f32x4 acc = (a0 + a1) + (a2 + a3);

        // -- gather f/i/c/o in 4-lane groups, elementwise; h store ASAP --
        unsigned short* hxout = hx + (size_t)(t & 1) * NB * NH;
        float harr[4];
        #pragma unroll
        for (int r = 0; r < 4; ++r) {
            float fv = acc[r];
            float iv = __shfl_xor(fv, 1);
            float gv = __shfl_xor(fv, 2);
            float ov = __shfl_xor(fv, 3);
            if (active) {
                float ft = sigm(fv);
                float it = sigm(iv);
                float gt = tanh_f(gv);
                float ot = sigm(ov);
                float Cn = ft * Cst[r] + it * gt;
                Cst[r] = Cn;
                float ht = ot * tanh_f(Cn);
                harr[r] = ht;
                int m = kg * 4 + r;               // batch within cluster
                __hip_bfloat16 hb = __float2bfloat16(ht);
                __hip_atomic_store(
                    (unsigned short*)(hxout + (size_t)(cl * 8 + m) * NH + j),
                    *(unsigned short*)&hb,
                    __ATOMIC_RELAXED, __HIP_MEMORY_SCOPE_AGENT);
            }
        }

        // -- publish: drain h stores, then one 4B per-wave flag store --
        asm volatile("s_waitcnt vmcnt(0)" ::: "memory");
        if (lane == 0)
            __hip_atomic_store(fb + myflag, (unsigned int)(t + 1),
                               __ATOMIC_RELAXED, __HIP_MEMORY_SCOPE_AGENT);

        // -- fp32 output stores AFTER publish (off the critical path) --
        if (active) {
            #pragma unroll
            for (int r = 0; r < 4; ++r) {
                int m = kg * 4 + r;
                out[((size_t)t * NB + cl * 8 + m) * NH + j] = harr[r];
            }
        }
    }
}

extern "C" void kernel_launch(void* const* d_in, const int* in_sizes, int n_in,
                              void* d_out, int out_size, void* d_ws, size_t ws_size,
                              hipStream_t stream) {
    const float* x  = (const float*)d_in[0];
    const float* h0 = (const float*)d_in[1];
    const float* c0 = (const float*)d_in[2];
    const float* Wf = (const float*)d_in[3];
    const float* Bf = (const float*)d_in[4];
    const float* Wi = (const float*)d_in[5];
    const float* Bi = (const float*)d_in[6];
    const float* Wc = (const float*)d_in[7];
    const float* Bc = (const float*)d_in[8];
    const float* Wo = (const float*)d_in[9];
    const float* Bo = (const float*)d_in[10];
    float* out = (float*)d_out;

    // Zero the flag array each launch (monotonic flags must restart at 0;
    // d_ws is not re-poisoned between graph replays). hx needs no init —
    // every read is gated by this launch's flags.
    hipMemsetAsync(d_ws, 0, ZERO_BYTES, stream);

    lstm_fused<<<dim3(256), dim3(256), 0, stream>>>(
        x, h0, c0, Wf, Bf, Wi, Bi, Wc, Bc, Wo, Bo, out,
        (unsigned char*)d_ws);
}